// Round 1
// baseline (730.965 us; speedup 1.0000x reference)
//
#include <hip/hip_runtime.h>
#include <hip/hip_bf16.h>

// Fused 2-layer LSTM (H=32) + final linear head, MI355X gfx950.
// B=4096, T=512, D=28. One WG (2 waves) per 16-row batch tile, 256 WGs.
// Gates via mfma_f32_16x16x32_bf16 with hi/lo bf16 split (≈fp32 exact).
// Wave w owns gate N-tiles {2t+w} => units [16w,16w+16): i,f,g,o of a unit
// land in the same lane (C layout col=lane&15). h redistributed C-frag ->
// A-frag through LDS (rows padded to 40 shorts = 80B), double-buffered by
// step parity; exactly one __syncthreads per timestep.

#define T_LEN 512
#define D_IN  28

typedef __attribute__((ext_vector_type(8))) short short8;  // 8 x bf16
typedef __attribute__((ext_vector_type(4))) float f32x4;

__device__ __forceinline__ float fsig(float x) {
  float e = __builtin_amdgcn_exp2f(x * -1.4426950408889634f);
  return __builtin_amdgcn_rcpf(1.0f + e);
}
__device__ __forceinline__ float ftanh(float x) {
  float e = __builtin_amdgcn_exp2f(x * 2.8853900817779268f);
  return 1.0f - 2.0f * __builtin_amdgcn_rcpf(e + 1.0f);
}

// hi = bf16 truncation of x (exact residual), lo = bf16 of (x - hi).
__device__ __forceinline__ void split_bf16(float x, short& hi, short& lo) {
  unsigned u = __float_as_uint(x);
  hi = (short)(u >> 16);
  float hf = __uint_as_float(u & 0xFFFF0000u);
  float lf = x - hf;  // exact
  lo = (short)(__float_as_uint(lf) >> 16);
}

// Load one 16-col B-operand tile (K=32 x N=16) of W (row-major G x ldk),
// gate rows n*16..n*16+15, k zero-padded past kvalid. Lane l: col=l&15,
// k = (l>>4)*8 .. +8 (8 consecutive bf16 per lane).
template <int KVALID>
__device__ __forceinline__ void load_wtile(const float* __restrict__ W, int ldk,
                                           int n, int lane, short8& hi, short8& lo) {
  int row = n * 16 + (lane & 15);
  int kb = (lane >> 4) * 8;
  const float* p = W + row * ldk + kb;
#pragma unroll
  for (int i = 0; i < 8; ++i) {
    float v = (kb + i < KVALID) ? p[i] : 0.0f;
    short h, l;
    split_bf16(v, h, l);
    hi[i] = h; lo[i] = l;
  }
}

#define MFMA(a, b, c) __builtin_amdgcn_mfma_f32_16x16x32_bf16(a, b, c, 0, 0, 0)

__global__ __launch_bounds__(128) void lstm2_fused(
    const float* __restrict__ x, const float* __restrict__ wih0,
    const float* __restrict__ whh0, const float* __restrict__ wih1,
    const float* __restrict__ whh1, const float* __restrict__ wout,
    const float* __restrict__ bout, float* __restrict__ out) {
  __shared__ short h1buf[2][2][16][40];  // [parity][hi/lo][row][unit pad 40]
  __shared__ short h2buf[2][2][16][40];
  __shared__ float hf[16][33];

  const int tid = threadIdx.x;
  const int lane = tid & 63;
  const int wid = tid >> 6;  // 0..1
  const int b0 = blockIdx.x * 16;

  for (int i = tid; i < 2 * 2 * 16 * 40; i += 128) {
    ((short*)h1buf)[i] = 0;
    ((short*)h2buf)[i] = 0;
  }

  const int lrow = lane & 15;   // A-frag row / C-frag col
  const int lgrp = lane >> 4;   // 0..3
  const int kb = lgrp * 8;      // A/B-frag k base
  const int uu = lrow + 16 * wid;  // unit owned in elementwise phase

  // ---- weight fragments in VGPRs (hi/lo bf16), loaded once ----
  short8 Wih0h[4], Wih0l[4], Whh0h[4], Whh0l[4];
  short8 Wih1h[4], Wih1l[4], Whh1h[4], Whh1l[4];
#pragma unroll
  for (int tt = 0; tt < 4; ++tt) {
    int n = tt * 2 + wid;
    load_wtile<28>(wih0, 28, n, lane, Wih0h[tt], Wih0l[tt]);
    load_wtile<32>(whh0, 32, n, lane, Whh0h[tt], Whh0l[tt]);
    load_wtile<32>(wih1, 32, n, lane, Wih1h[tt], Wih1l[tt]);
    load_wtile<32>(whh1, 32, n, lane, Whh1h[tt], Whh1l[tt]);
  }

  float c1[4] = {0, 0, 0, 0}, c2[4] = {0, 0, 0, 0};
  float h1v[4] = {0, 0, 0, 0}, h2v[4] = {0, 0, 0, 0};

  // x A-frag source: row b0+lrow, features kb..kb+7 (chunk 3: 24..27 + pad)
  const float* xrow = x + ((size_t)(b0 + lrow)) * T_LEN * D_IN + kb;
  float4 A0, A1;
  A0 = *(const float4*)(xrow);
  A1 = (lgrp < 3) ? *(const float4*)(xrow + 4) : make_float4(0, 0, 0, 0);

  __syncthreads();  // LDS zero-init visible

  for (int t = 0; t < T_LEN; ++t) {
    const int wp = t & 1, rp = wp ^ 1;

    // prefetch next step's x
    int tn = (t + 1 < T_LEN) ? t + 1 : t;
    float4 N0 = *(const float4*)(xrow + (size_t)tn * D_IN);
    float4 N1 = (lgrp < 3) ? *(const float4*)(xrow + (size_t)tn * D_IN + 4)
                           : make_float4(0, 0, 0, 0);

    // current x -> hi/lo bf16 A-frag
    short8 xh, xl;
    {
      float xv[8] = {A0.x, A0.y, A0.z, A0.w, A1.x, A1.y, A1.z, A1.w};
#pragma unroll
      for (int i = 0; i < 8; ++i) {
        short h, l;
        split_bf16(xv[i], h, l);
        xh[i] = h; xl[i] = l;
      }
    }

    // ---- layer 1 ----
    short8 p1h = *(const short8*)&h1buf[rp][0][lrow][kb];
    short8 p1l = *(const short8*)&h1buf[rp][1][lrow][kb];

    f32x4 acc[4];
#pragma unroll
    for (int tt = 0; tt < 4; ++tt) {
      f32x4 a = {0.f, 0.f, 0.f, 0.f};
      a = MFMA(xh, Wih0h[tt], a);
      a = MFMA(xl, Wih0h[tt], a);
      a = MFMA(xh, Wih0l[tt], a);
      a = MFMA(p1h, Whh0h[tt], a);
      a = MFMA(p1l, Whh0h[tt], a);
      a = MFMA(p1h, Whh0l[tt], a);
      acc[tt] = a;
    }

#pragma unroll
    for (int r = 0; r < 4; ++r) {
      float ig = fsig(acc[0][r]);
      float fg = fsig(acc[1][r]);
      float gg = ftanh(acc[2][r]);
      float og = fsig(acc[3][r]);
      c1[r] = fg * c1[r] + ig * gg;
      h1v[r] = og * ftanh(c1[r]);
      int row = lgrp * 4 + r;
      short hh_, ll_;
      split_bf16(h1v[r], hh_, ll_);
      h1buf[wp][0][row][uu] = hh_;
      h1buf[wp][1][row][uu] = ll_;
    }

    __syncthreads();  // h1(t) complete; also orders prev-parity buffer reuse

    // ---- layer 2 ----
    short8 a1h = *(const short8*)&h1buf[wp][0][lrow][kb];
    short8 a1l = *(const short8*)&h1buf[wp][1][lrow][kb];
    short8 p2h = *(const short8*)&h2buf[rp][0][lrow][kb];
    short8 p2l = *(const short8*)&h2buf[rp][1][lrow][kb];

#pragma unroll
    for (int tt = 0; tt < 4; ++tt) {
      f32x4 a = {0.f, 0.f, 0.f, 0.f};
      a = MFMA(a1h, Wih1h[tt], a);
      a = MFMA(a1l, Wih1h[tt], a);
      a = MFMA(a1h, Wih1l[tt], a);
      a = MFMA(p2h, Whh1h[tt], a);
      a = MFMA(p2l, Whh1h[tt], a);
      a = MFMA(p2h, Whh1l[tt], a);
      acc[tt] = a;
    }

#pragma unroll
    for (int r = 0; r < 4; ++r) {
      float ig = fsig(acc[0][r]);
      float fg = fsig(acc[1][r]);
      float gg = ftanh(acc[2][r]);
      float og = fsig(acc[3][r]);
      c2[r] = fg * c2[r] + ig * gg;
      h2v[r] = og * ftanh(c2[r]);
      int row = lgrp * 4 + r;
      short hh_, ll_;
      split_bf16(h2v[r], hh_, ll_);
      h2buf[wp][0][row][uu] = hh_;
      h2buf[wp][1][row][uu] = ll_;
    }

    A0 = N0; A1 = N1;
    // no barrier here: next-iter L1 reads h1buf[wp] (written pre-barrier),
    // writes go to the opposite parity; all hazards ordered by the one
    // mid-step barrier (max inter-wave skew = half a step, accesses disjoint).
  }

  // ---- epilogue: out = h2_last @ wout^T + bout ----
#pragma unroll
  for (int r = 0; r < 4; ++r) hf[lgrp * 4 + r][uu] = h2v[r];
  __syncthreads();

  for (int j = tid; j < 160; j += 128) {
    int row = j / 10, col = j % 10;
    float s = bout[col];
#pragma unroll
    for (int u = 0; u < 32; ++u) s += hf[row][u] * wout[col * 32 + u];
    out[(size_t)(b0 + row) * 10 + col] = s;
  }
}

extern "C" void kernel_launch(void* const* d_in, const int* in_sizes, int n_in,
                              void* d_out, int out_size, void* d_ws, size_t ws_size,
                              hipStream_t stream) {
  const float* x = (const float*)d_in[0];
  const float* wih0 = (const float*)d_in[1];
  const float* whh0 = (const float*)d_in[2];
  const float* wih1 = (const float*)d_in[3];
  const float* whh1 = (const float*)d_in[4];
  const float* wout = (const float*)d_in[5];
  const float* bout = (const float*)d_in[6];
  float* out = (float*)d_out;
  lstm2_fused<<<256, 128, 0, stream>>>(x, wih0, whh0, wih1, whh1, wout, bout, out);
}

// Round 2
// 463.685 us; speedup vs baseline: 1.5764x; 1.5764x over previous
//
#include <hip/hip_runtime.h>
#include <hip/hip_bf16.h>

// Fused 2-layer LSTM (H=32) + linear head, MI355X gfx950.
// Layer-pipelined: WG = 4 waves; waves 0-1 compute layer 1 at time s,
// waves 2-3 compute layer 2 at time s-1 (classic wavefront pipeline).
// One __syncthreads per step covers both layers: every wave reads LDS
// parity q = (s&1)^1 and writes parity p = s&1.
// Gates via mfma_f32_16x16x32_bf16 with hi/lo bf16 split (≈fp32 exact).

#define T_LEN 512
#define D_IN  28

typedef __attribute__((ext_vector_type(8))) short short8;  // 8 x bf16
typedef __attribute__((ext_vector_type(4))) float f32x4;

__device__ __forceinline__ float fsig(float x) {
  float e = __builtin_amdgcn_exp2f(x * -1.4426950408889634f);
  return __builtin_amdgcn_rcpf(1.0f + e);
}
__device__ __forceinline__ float ftanh(float x) {
  float e = __builtin_amdgcn_exp2f(x * 2.8853900817779268f);
  return 1.0f - 2.0f * __builtin_amdgcn_rcpf(e + 1.0f);
}

// hi = bf16 truncation of x, lo = bf16 of exact residual (x - hi).
__device__ __forceinline__ void split_bf16(float x, short& hi, short& lo) {
  unsigned u = __float_as_uint(x);
  hi = (short)(u >> 16);
  float hf_ = __uint_as_float(u & 0xFFFF0000u);
  float lf = x - hf_;  // exact
  lo = (short)(__float_as_uint(lf) >> 16);
}

// B-operand tile (K=32 x N=16) of W (row-major G x ldk), gate rows
// n*16..n*16+15, k zero-padded past kval. Lane l: col=l&15, k=(l>>4)*8..+8.
__device__ __forceinline__ void load_wtile(const float* __restrict__ W, int ldk,
                                           int kval, int n, int lane,
                                           short8& hi, short8& lo) {
  int row = n * 16 + (lane & 15);
  int kb = (lane >> 4) * 8;
  const float* p = W + row * ldk + kb;
#pragma unroll
  for (int i = 0; i < 8; ++i) {
    float v = (kb + i < kval) ? p[i] : 0.0f;
    short h, l;
    split_bf16(v, h, l);
    hi[i] = h; lo[i] = l;
  }
}

#define MFMA(a, b, c) __builtin_amdgcn_mfma_f32_16x16x32_bf16(a, b, c, 0, 0, 0)

__global__ __launch_bounds__(256) void lstm2_pipe(
    const float* __restrict__ x, const float* __restrict__ wih0,
    const float* __restrict__ whh0, const float* __restrict__ wih1,
    const float* __restrict__ whh1, const float* __restrict__ wout,
    const float* __restrict__ bout, float* __restrict__ out) {
  __shared__ short h1buf[2][2][16][40];  // [parity][hi/lo][row][unit pad 40]
  __shared__ short h2buf[2][2][16][40];
  __shared__ float hf[16][33];

  const int tid = threadIdx.x;
  const int lane = tid & 63;
  const int wid = tid >> 6;    // 0..3
  const int layer = wid >> 1;  // 0 => L1 waves, 1 => L2 waves
  const int w01 = wid & 1;     // which unit-half within the layer
  const int b0 = blockIdx.x * 16;

  for (int i = tid; i < 2 * 2 * 16 * 40; i += 256) {
    ((short*)h1buf)[i] = 0;
    ((short*)h2buf)[i] = 0;
  }

  const int lrow = lane & 15;  // A-frag row / C-frag col
  const int lgrp = lane >> 4;  // 0..3
  const int kb = lgrp * 8;
  const int uu = lrow + 16 * w01;  // unit owned in elementwise phase

  // ---- this wave's layer weights in VGPRs (hi/lo bf16) ----
  const float* Wih = layer ? wih1 : wih0;
  const float* Whh = layer ? whh1 : whh0;
  const int ldk = layer ? 32 : 28;

  short8 Wxh[4], Wxl[4], Whh_[4], Whl[4];
#pragma unroll
  for (int tt = 0; tt < 4; ++tt) {
    int n = tt * 2 + w01;
    load_wtile(Wih, ldk, ldk, n, lane, Wxh[tt], Wxl[tt]);
    load_wtile(Whh, 32, 32, n, lane, Whh_[tt], Whl[tt]);
  }

  float c[4] = {0, 0, 0, 0}, h[4] = {0, 0, 0, 0};

  const float* xrow = x + ((size_t)(b0 + lrow)) * T_LEN * D_IN + kb;
  float4 A0 = make_float4(0, 0, 0, 0), A1 = make_float4(0, 0, 0, 0);
  if (layer == 0) {
    A0 = *(const float4*)(xrow);
    if (lgrp < 3) A1 = *(const float4*)(xrow + 4);
  }

  __syncthreads();  // LDS zero-init visible

  for (int s = 0; s < T_LEN + 1; ++s) {
    const int p = s & 1, q = p ^ 1;
    if (layer == 0) {
      if (s < T_LEN) {
        // prefetch x(s+1)
        int tn = (s + 1 < T_LEN) ? s + 1 : s;
        float4 N0 = *(const float4*)(xrow + (size_t)tn * D_IN);
        float4 N1 = make_float4(0, 0, 0, 0);
        if (lgrp < 3) N1 = *(const float4*)(xrow + (size_t)tn * D_IN + 4);

        short8 xh, xl;
        {
          float xv[8] = {A0.x, A0.y, A0.z, A0.w, A1.x, A1.y, A1.z, A1.w};
#pragma unroll
          for (int i = 0; i < 8; ++i) {
            short hh_, ll_;
            split_bf16(xv[i], hh_, ll_);
            xh[i] = hh_; xl[i] = ll_;
          }
        }
        short8 ph = *(const short8*)&h1buf[q][0][lrow][kb];
        short8 pl = *(const short8*)&h1buf[q][1][lrow][kb];
        f32x4 acc[4];
#pragma unroll
        for (int tt = 0; tt < 4; ++tt) {
          f32x4 a = {0.f, 0.f, 0.f, 0.f};
          a = MFMA(xh, Wxh[tt], a);
          a = MFMA(xl, Wxh[tt], a);
          a = MFMA(xh, Wxl[tt], a);
          a = MFMA(ph, Whh_[tt], a);
          a = MFMA(pl, Whh_[tt], a);
          a = MFMA(ph, Whl[tt], a);
          acc[tt] = a;
        }
#pragma unroll
        for (int r = 0; r < 4; ++r) {
          float ig = fsig(acc[0][r]);
          float fg = fsig(acc[1][r]);
          float gg = ftanh(acc[2][r]);
          float og = fsig(acc[3][r]);
          c[r] = fg * c[r] + ig * gg;
          h[r] = og * ftanh(c[r]);
          short hh_, ll_;
          split_bf16(h[r], hh_, ll_);
          int row = lgrp * 4 + r;
          h1buf[p][0][row][uu] = hh_;
          h1buf[p][1][row][uu] = ll_;
        }
        A0 = N0; A1 = N1;
      }
    } else {
      if (s >= 1) {
        short8 ah = *(const short8*)&h1buf[q][0][lrow][kb];
        short8 al = *(const short8*)&h1buf[q][1][lrow][kb];
        short8 ph = *(const short8*)&h2buf[q][0][lrow][kb];
        short8 pl = *(const short8*)&h2buf[q][1][lrow][kb];
        f32x4 acc[4];
#pragma unroll
        for (int tt = 0; tt < 4; ++tt) {
          f32x4 a = {0.f, 0.f, 0.f, 0.f};
          a = MFMA(ah, Wxh[tt], a);
          a = MFMA(al, Wxh[tt], a);
          a = MFMA(ah, Wxl[tt], a);
          a = MFMA(ph, Whh_[tt], a);
          a = MFMA(pl, Whh_[tt], a);
          a = MFMA(ph, Whl[tt], a);
          acc[tt] = a;
        }
#pragma unroll
        for (int r = 0; r < 4; ++r) {
          float ig = fsig(acc[0][r]);
          float fg = fsig(acc[1][r]);
          float gg = ftanh(acc[2][r]);
          float og = fsig(acc[3][r]);
          c[r] = fg * c[r] + ig * gg;
          h[r] = og * ftanh(c[r]);
          short hh_, ll_;
          split_bf16(h[r], hh_, ll_);
          int row = lgrp * 4 + r;
          h2buf[p][0][row][uu] = hh_;
          h2buf[p][1][row][uu] = ll_;
        }
      }
    }
    __syncthreads();
    // Hazard audit: iter s reads parity q, writes parity p. Writes at iter
    // s+1 hit parity q — ordered against iter-s reads by this barrier
    // (lgkmcnt(0) drained before s_barrier). One barrier/step total.
  }

  // ---- epilogue: out = h2(T-1) @ wout^T + bout ----
  if (layer == 1) {
#pragma unroll
    for (int r = 0; r < 4; ++r) hf[lgrp * 4 + r][uu] = h[r];
  }
  __syncthreads();

  for (int j = tid; j < 160; j += 256) {
    int row = j / 10, col = j % 10;
    float s = bout[col];
#pragma unroll
    for (int u = 0; u < 32; ++u) s += hf[row][u] * wout[col * 32 + u];
    out[(size_t)(b0 + row) * 10 + col] = s;
  }
}

extern "C" void kernel_launch(void* const* d_in, const int* in_sizes, int n_in,
                              void* d_out, int out_size, void* d_ws, size_t ws_size,
                              hipStream_t stream) {
  const float* x = (const float*)d_in[0];
  const float* wih0 = (const float*)d_in[1];
  const float* whh0 = (const float*)d_in[2];
  const float* wih1 = (const float*)d_in[3];
  const float* whh1 = (const float*)d_in[4];
  const float* wout = (const float*)d_in[5];
  const float* bout = (const float*)d_in[6];
  float* out = (float*)d_out;
  lstm2_pipe<<<256, 256, 0, stream>>>(x, wih0, whh0, wih1, whh1, wout, bout, out);
}